// Round 3
// baseline (124.652 us; speedup 1.0000x reference)
//
#include <hip/hip_runtime.h>

#define BATCH 131072
#define IN 128
#define OUT 128
#define PNUM 16
#define LDS_PITCH 136   // 128 + 8 f16 pad: ds_read_b128 lanes land 2-way max (free)
#define NITER 4
#define ROWS_PER_BLOCK (64 * NITER)   // 4 waves x 16 rows x 4 tiles

typedef _Float16 f16x8 __attribute__((ext_vector_type(8)));
typedef float f32x4 __attribute__((ext_vector_type(4)));

// w[o*IN + i] = (f16) sum_p coef[o][i][p]
__global__ __launch_bounds__(256) void prep_w_kernel(const float* __restrict__ coef,
                                                     _Float16* __restrict__ w) {
    int t = blockIdx.x * blockDim.x + threadIdx.x;
    const float4* p = (const float4*)(coef + (size_t)t * PNUM);
    float4 a = p[0], b = p[1], c = p[2], d = p[3];
    float s = (a.x + a.y + a.z + a.w) + (b.x + b.y + b.z + b.w)
            + (c.x + c.y + c.z + c.w) + (d.x + d.y + d.z + d.w);
    w[t] = (_Float16)s;
}

// 256 threads (4 waves), each wave 16 rows; block streams 4 consecutive 64-row
// tiles. w staged to LDS once (w-loads issued FIRST: in-order vmcnt means the
// pre-barrier ds_write then only drains w, not x). Loop body: prefetch x(t+1)
// -> tanh(t) -> MFMA(t) -> nt-store(t); no barrier inside the loop, so reads of
// tile t+1 overlap compute+stores of tile t and the chip sustains R/W overlap.
__global__ __launch_bounds__(256, 2) void gemm_tanh_kernel(const float* __restrict__ x,
                                                           const _Float16* __restrict__ w,
                                                           const float* __restrict__ trange,
                                                           float* __restrict__ out) {
    __shared__ _Float16 wlds[OUT * LDS_PITCH];

    // tanh(v) = 1 - 2/(exp2(v * 2*log2e) + 1); fold t and 2*log2e into one scale
    const float ts = trange[0] * 2.8853900817779268f;
    const int tid  = threadIdx.x;
    const int lane = tid & 63;
    const int wv   = tid >> 6;        // 0..3
    const int m = lane & 15;
    const int q = lane >> 4;

    // 1. cooperative stage of w (32 KB, L2-resident): 64 f16 per thread.
    //    Issued before any x load so the barrier does not wait on x.
#pragma unroll
    for (int i = 0; i < 8; ++i) {
        int idx = (i * 256 + tid) * 8;          // f16 index, 8 per thread per pass
        int r = idx >> 7;
        int c = idx & 127;
        *(f16x8*)&wlds[r * LDS_PITCH + c] = *(const f16x8*)(w + idx);
    }

    const size_t base_row = (size_t)blockIdx.x * ROWS_PER_BLOCK + (size_t)wv * 16 + m;

    // 2. prologue: x loads for tile 0 (8 independent dwordx4 per lane)
    f32x4 xv[2][8];
    {
        const float* xr = x + base_row * IN;
#pragma unroll
        for (int ks = 0; ks < 4; ++ks) {
            xv[0][2 * ks]     = *reinterpret_cast<const f32x4*>(xr + ks * 32 + q * 8);
            xv[0][2 * ks + 1] = *reinterpret_cast<const f32x4*>(xr + ks * 32 + q * 8 + 4);
        }
    }
    __syncthreads();

#pragma unroll
    for (int it = 0; it < NITER; ++it) {
        const int cur = it & 1;   // compile-time after unroll (no scratch)

        // 2a. prefetch next tile's x before touching this tile's data
        if (it + 1 < NITER) {
            const float* xr = x + (base_row + (size_t)(it + 1) * 64) * IN;
#pragma unroll
            for (int ks = 0; ks < 4; ++ks) {
                xv[cur ^ 1][2 * ks]     = *reinterpret_cast<const f32x4*>(xr + ks * 32 + q * 8);
                xv[cur ^ 1][2 * ks + 1] = *reinterpret_cast<const f32x4*>(xr + ks * 32 + q * 8 + 4);
            }
        }

        // 3. tanh + cvt -> B fragments (waits only on this tile's loads;
        //    the 8 prefetch loads stay outstanding: vmcnt(8))
        f16x8 af[4];
#pragma unroll
        for (int ks = 0; ks < 4; ++ks) {
            f32x4 a = xv[cur][2 * ks], b = xv[cur][2 * ks + 1];
#pragma unroll
            for (int e = 0; e < 4; ++e) {
                float ea = __builtin_amdgcn_exp2f(a[e] * ts);
                float eb = __builtin_amdgcn_exp2f(b[e] * ts);
                af[ks][e]     = (_Float16)__builtin_fmaf(-2.0f, __builtin_amdgcn_rcpf(ea + 1.0f), 1.0f);
                af[ks][e + 4] = (_Float16)__builtin_fmaf(-2.0f, __builtin_amdgcn_rcpf(eb + 1.0f), 1.0f);
            }
        }

        // 4. MFMA over all 8 col-tiles; A = w (from LDS), B = tanh(x) fragment
        f32x4 acc[8];
#pragma unroll
        for (int nt = 0; nt < 8; ++nt) acc[nt] = (f32x4){0.f, 0.f, 0.f, 0.f};

#pragma unroll
        for (int ks = 0; ks < 4; ++ks) {
            const int kb = ks * 32 + q * 8;
#pragma unroll
            for (int nt = 0; nt < 8; ++nt) {
                f16x8 bf = *(const f16x8*)&wlds[(nt * 16 + m) * LDS_PITCH + kb];
                acc[nt] = __builtin_amdgcn_mfma_f32_16x16x32_f16(bf, af[ks], acc[nt], 0, 0, 0);
            }
        }

        // 5. store: lane (m,q) holds out[row][nt*16 + q*4 .. +3] -> dwordx4,
        //    nontemporal (write-once; per instr 16 rows x 64B full granules)
        float* orow = out + (base_row + (size_t)it * 64) * OUT + q * 4;
#pragma unroll
        for (int nt = 0; nt < 8; ++nt) {
            __builtin_nontemporal_store(acc[nt], reinterpret_cast<f32x4*>(orow + nt * 16));
        }
    }
}

extern "C" void kernel_launch(void* const* d_in, const int* in_sizes, int n_in,
                              void* d_out, int out_size, void* d_ws, size_t ws_size,
                              hipStream_t stream) {
    const float* x    = (const float*)d_in[0];
    const float* coef = (const float*)d_in[1];
    const float* tr   = (const float*)d_in[2];
    float* out = (float*)d_out;
    _Float16* w = (_Float16*)d_ws;   // 32 KB scratch

    prep_w_kernel<<<(OUT * IN) / 256, 256, 0, stream>>>(coef, w);
    gemm_tanh_kernel<<<BATCH / ROWS_PER_BLOCK, 256, 0, stream>>>(x, w, tr, out);
}

// Round 4
// 122.174 us; speedup vs baseline: 1.0203x; 1.0203x over previous
//
#include <hip/hip_runtime.h>

#define BATCH 131072
#define IN 128
#define OUT 128
#define PNUM 16
#define LDS_PITCH 136   // 128 + 8 f16 pad: ds_read_b128 lanes land 2-way max (free)
#define NITER 4
#define ROWS_PER_BLOCK (64 * NITER)   // 4 waves x 16 rows x 4 tiles

typedef _Float16 f16x8 __attribute__((ext_vector_type(8)));
typedef float f32x4 __attribute__((ext_vector_type(4)));

// w[o*IN + i] = (f16) sum_p coef[o][i][p]
__global__ __launch_bounds__(256) void prep_w_kernel(const float* __restrict__ coef,
                                                     _Float16* __restrict__ w) {
    int t = blockIdx.x * blockDim.x + threadIdx.x;
    const float4* p = (const float4*)(coef + (size_t)t * PNUM);
    float4 a = p[0], b = p[1], c = p[2], d = p[3];
    float s = (a.x + a.y + a.z + a.w) + (b.x + b.y + b.z + b.w)
            + (c.x + c.y + c.z + c.w) + (d.x + d.y + d.z + d.w);
    w[t] = (_Float16)s;
}

// 256 threads (4 waves), each wave 16 rows; block streams 4 consecutive 64-row
// tiles with register double-buffered x.
// KEY FIX vs round 3: VGPR_Count=40 proved the compiler was SINKING the 8
// x-loads to their uses (per-wave MLP ~2 -> latency-bound at 2.5 TB/s).
// sched_barrier(0) after each load batch pins all 8 loads to issue together;
// the prefetched 8 KB/wave stays outstanding across the whole compute phase.
__global__ __launch_bounds__(256, 2) void gemm_tanh_kernel(const float* __restrict__ x,
                                                           const _Float16* __restrict__ w,
                                                           const float* __restrict__ trange,
                                                           float* __restrict__ out) {
    __shared__ _Float16 wlds[OUT * LDS_PITCH];

    // tanh(v) = 1 - 2/(exp2(v * 2*log2e) + 1); fold t and 2*log2e into one scale
    const float ts = trange[0] * 2.8853900817779268f;
    const int tid  = threadIdx.x;
    const int lane = tid & 63;
    const int wv   = tid >> 6;        // 0..3
    const int m = lane & 15;
    const int q = lane >> 4;

    // 1. cooperative stage of w (32 KB, L2-resident): 64 f16 per thread.
#pragma unroll
    for (int i = 0; i < 8; ++i) {
        int idx = (i * 256 + tid) * 8;          // f16 index, 8 per thread per pass
        int r = idx >> 7;
        int c = idx & 127;
        *(f16x8*)&wlds[r * LDS_PITCH + c] = *(const f16x8*)(w + idx);
    }

    const size_t base_row = (size_t)blockIdx.x * ROWS_PER_BLOCK + (size_t)wv * 16 + m;

    // 2. prologue: x loads for tile 0 (8 independent dwordx4 per lane)
    f32x4 xv[2][8];
    {
        const float* xr = x + base_row * IN;
#pragma unroll
        for (int ks = 0; ks < 4; ++ks) {
            xv[0][2 * ks]     = *reinterpret_cast<const f32x4*>(xr + ks * 32 + q * 8);
            xv[0][2 * ks + 1] = *reinterpret_cast<const f32x4*>(xr + ks * 32 + q * 8 + 4);
        }
    }
    __builtin_amdgcn_sched_barrier(0);   // pin: prologue loads issue before anything below
    __syncthreads();

#pragma unroll
    for (int it = 0; it < NITER; ++it) {
        const int cur = it & 1;   // compile-time after unroll (no scratch)

        // 2a. prefetch next tile's x; sched_barrier pins all 8 loads HERE,
        //     before the tanh/MFMA of the current tile (keeps 8 KB/wave in flight)
        if (it + 1 < NITER) {
            const float* xr = x + (base_row + (size_t)(it + 1) * 64) * IN;
#pragma unroll
            for (int ks = 0; ks < 4; ++ks) {
                xv[cur ^ 1][2 * ks]     = *reinterpret_cast<const f32x4*>(xr + ks * 32 + q * 8);
                xv[cur ^ 1][2 * ks + 1] = *reinterpret_cast<const f32x4*>(xr + ks * 32 + q * 8 + 4);
            }
        }
        __builtin_amdgcn_sched_barrier(0);

        // 3. tanh + cvt -> B fragments (waits only on this tile's loads;
        //    the 8 prefetch loads stay outstanding: vmcnt(8))
        f16x8 af[4];
#pragma unroll
        for (int ks = 0; ks < 4; ++ks) {
            f32x4 a = xv[cur][2 * ks], b = xv[cur][2 * ks + 1];
#pragma unroll
            for (int e = 0; e < 4; ++e) {
                float ea = __builtin_amdgcn_exp2f(a[e] * ts);
                float eb = __builtin_amdgcn_exp2f(b[e] * ts);
                af[ks][e]     = (_Float16)__builtin_fmaf(-2.0f, __builtin_amdgcn_rcpf(ea + 1.0f), 1.0f);
                af[ks][e + 4] = (_Float16)__builtin_fmaf(-2.0f, __builtin_amdgcn_rcpf(eb + 1.0f), 1.0f);
            }
        }

        // 4. MFMA over all 8 col-tiles; A = w (from LDS), B = tanh(x) fragment
        f32x4 acc[8];
#pragma unroll
        for (int nt = 0; nt < 8; ++nt) acc[nt] = (f32x4){0.f, 0.f, 0.f, 0.f};

#pragma unroll
        for (int ks = 0; ks < 4; ++ks) {
            const int kb = ks * 32 + q * 8;
#pragma unroll
            for (int nt = 0; nt < 8; ++nt) {
                f16x8 bf = *(const f16x8*)&wlds[(nt * 16 + m) * LDS_PITCH + kb];
                acc[nt] = __builtin_amdgcn_mfma_f32_16x16x32_f16(bf, af[ks], acc[nt], 0, 0, 0);
            }
        }

        // 5. store: lane (m,q) holds out[row][nt*16 + q*4 .. +3] -> dwordx4,
        //    nontemporal (write-once; per instr 16 rows x 64B full granules)
        float* orow = out + (base_row + (size_t)it * 64) * OUT + q * 4;
#pragma unroll
        for (int nt = 0; nt < 8; ++nt) {
            __builtin_nontemporal_store(acc[nt], reinterpret_cast<f32x4*>(orow + nt * 16));
        }
    }
}

extern "C" void kernel_launch(void* const* d_in, const int* in_sizes, int n_in,
                              void* d_out, int out_size, void* d_ws, size_t ws_size,
                              hipStream_t stream) {
    const float* x    = (const float*)d_in[0];
    const float* coef = (const float*)d_in[1];
    const float* tr   = (const float*)d_in[2];
    float* out = (float*)d_out;
    _Float16* w = (_Float16*)d_ws;   // 32 KB scratch

    prep_w_kernel<<<(OUT * IN) / 256, 256, 0, stream>>>(coef, w);
    gemm_tanh_kernel<<<BATCH / ROWS_PER_BLOCK, 256, 0, stream>>>(x, w, tr, out);
}

// Round 6
// 116.099 us; speedup vs baseline: 1.0737x; 1.0523x over previous
//
#include <hip/hip_runtime.h>

#define BATCH 131072
#define IN 128
#define OUT 128
#define PNUM 16
#define WPITCH 136   // f16 pitch, w tile: 272B rows, frag reads land conflict-free
#define XPITCH 136   // f16 pitch, x bounce: same geometry as w tile
#define OPITCH 132   // f32 pitch, out bounce: 528B rows -> slot (33m+4nt+q)%8, 2-way max

typedef _Float16 f16x8 __attribute__((ext_vector_type(8)));
typedef _Float16 f16x4 __attribute__((ext_vector_type(4)));
typedef float f32x4 __attribute__((ext_vector_type(4)));

// w[o*IN + i] = (f16) sum_p coef[o][i][p]
__global__ __launch_bounds__(256) void prep_w_kernel(const float* __restrict__ coef,
                                                     _Float16* __restrict__ w) {
    int t = blockIdx.x * blockDim.x + threadIdx.x;
    const float4* p = (const float4*)(coef + (size_t)t * PNUM);
    float4 a = p[0], b = p[1], c = p[2], d = p[3];
    float s = (a.x + a.y + a.z + a.w) + (b.x + b.y + b.z + b.w)
            + (c.x + c.y + c.z + c.w) + (d.x + d.y + d.z + d.w);
    w[t] = (_Float16)s;
}

// 256 threads (4 waves), one-shot 64-row tile per block, grid 2048.
// EVERY global memory instruction is wave-contiguous (64 lanes x 16B = 1KB of
// two complete rows): rounds 0-4 all used per-lane-row scatter (16 rows x 64B
// segments per instruction) and ALL plateaued at ~43us / 2.5 TB/s mixed R/W —
// m146's wave-contiguous RMSNorm sustains 4.89 TB/s on this chip.
// Fragment scatter/gather happens in per-wave LDS bounce regions instead:
// whole-wave instruction order makes intra-wave ds_write -> ds_read safe with
// no barriers (only the w-stage barrier remains).
__global__ __launch_bounds__(256, 2) void gemm_tanh_kernel(const float* __restrict__ x,
                                                           const _Float16* __restrict__ w,
                                                           const float* __restrict__ trange,
                                                           float* __restrict__ out) {
    __shared__ _Float16 wlds[OUT * WPITCH];                      // 34816 B
    __shared__ __align__(16) unsigned char scratch[4][16 * OPITCH * 4]; // 4 x 8448 B

    // tanh(v) = 1 - 2/(exp2(v * 2*log2e) + 1); fold t and 2*log2e into one scale
    const float ts = trange[0] * 2.8853900817779268f;
    const int tid  = threadIdx.x;
    const int lane = tid & 63;
    const int wv   = tid >> 6;        // 0..3
    const int m    = lane & 15;
    const int q    = lane >> 4;       // 0..3
    const int s    = lane & 31;       // 0..31
    const int half = lane >> 5;       // 0..1

    // 1. w stage FIRST (in-order vmcnt: the barrier's ds_write wait drains only
    //    w loads, not the x loads issued below). 64 f16 per thread.
#pragma unroll
    for (int i = 0; i < 8; ++i) {
        int idx = (i * 256 + tid) * 8;          // f16 index, 8 per thread per pass
        int r = idx >> 7;
        int c = idx & 127;
        *(f16x8*)&wlds[r * WPITCH + c] = *(const f16x8*)(w + idx);
    }

    const int row0 = blockIdx.x * 64 + wv * 16;   // wave owns rows row0..row0+15

    // 2. coalesced x loads: instruction j covers rows row0+2j / row0+2j+1
    //    completely -> 1KB contiguous per instruction.
    f32x4 xv[8];
#pragma unroll
    for (int j = 0; j < 8; ++j) {
        xv[j] = *reinterpret_cast<const f32x4*>(
            x + (size_t)(row0 + 2 * j + half) * IN + s * 4);
    }
    __builtin_amdgcn_sched_barrier(0);   // keep the 8 loads batched (issue MLP)
    __syncthreads();                     // w tile visible to all waves

    _Float16* xb = (_Float16*)scratch[wv];   // 16 rows x XPITCH f16 (4352 B used)
    float*    ob = (float*)scratch[wv];      // 16 rows x OPITCH f32 (aliases xb;
                                             // sequential lifetimes, same wave)

    // 3. tanh -> f16, bounce into xb (row r, 8B per lane, 2-way banks max)
#pragma unroll
    for (int j = 0; j < 8; ++j) {
        f32x4 a = xv[j];
        f16x4 h;
#pragma unroll
        for (int e = 0; e < 4; ++e) {
            float ea = __builtin_amdgcn_exp2f(a[e] * ts);
            h[e] = (_Float16)__builtin_fmaf(-2.0f, __builtin_amdgcn_rcpf(ea + 1.0f), 1.0f);
        }
        *(f16x4*)&xb[(2 * j + half) * XPITCH + s * 4] = h;
    }

    // 4. A fragments: identical values to rounds 0-4, now via ds_read_b128.
    //    slot = (17m + 4ks + q) % 8 -> conflict-free in consecutive-lane groups.
    f16x8 af[4];
#pragma unroll
    for (int ks = 0; ks < 4; ++ks) {
        af[ks] = *(const f16x8*)&xb[m * XPITCH + ks * 32 + q * 8];
    }

    // 5. MFMA over all 8 col-tiles; A = w (from LDS), B = tanh(x) fragment.
    //    af[] is in registers before phase 6 overwrites the bounce region.
    f32x4 acc[8];
#pragma unroll
    for (int nt = 0; nt < 8; ++nt) acc[nt] = (f32x4){0.f, 0.f, 0.f, 0.f};

#pragma unroll
    for (int ks = 0; ks < 4; ++ks) {
        const int kb = ks * 32 + q * 8;
#pragma unroll
        for (int nt = 0; nt < 8; ++nt) {
            f16x8 bf = *(const f16x8*)&wlds[(nt * 16 + m) * WPITCH + kb];
            acc[nt] = __builtin_amdgcn_mfma_f32_16x16x32_f16(bf, af[ks], acc[nt], 0, 0, 0);
        }
    }

    // 6. bounce acc into ob: lane (m,q) owns out[row m][nt*16+q*4 ..+3]
#pragma unroll
    for (int nt = 0; nt < 8; ++nt) {
        *(f32x4*)&ob[m * OPITCH + nt * 16 + q * 4] = acc[nt];
    }

    // 7. linear read-back + coalesced stores: instruction j writes rows
    //    row0+2j / row0+2j+1 completely -> 1KB contiguous, plain cached.
#pragma unroll
    for (int j = 0; j < 8; ++j) {
        f32x4 o = *(const f32x4*)&ob[(2 * j + half) * OPITCH + s * 4];
        *reinterpret_cast<f32x4*>(out + (size_t)(row0 + 2 * j + half) * OUT + s * 4) = o;
    }
}

extern "C" void kernel_launch(void* const* d_in, const int* in_sizes, int n_in,
                              void* d_out, int out_size, void* d_ws, size_t ws_size,
                              hipStream_t stream) {
    const float* x    = (const float*)d_in[0];
    const float* coef = (const float*)d_in[1];
    const float* tr   = (const float*)d_in[2];
    float* out = (float*)d_out;
    _Float16* w = (_Float16*)d_ws;   // 32 KB scratch

    prep_w_kernel<<<(OUT * IN) / 256, 256, 0, stream>>>(coef, w);
    gemm_tanh_kernel<<<BATCH / 64, 256, 0, stream>>>(x, w, tr, out);
}